// Round 2
// baseline (1619.598 us; speedup 1.0000x reference)
//
#include <hip/hip_runtime.h>
#include <stdint.h>

typedef uint16_t u16;
typedef short bf16x8 __attribute__((ext_vector_type(8)));
typedef float f32x4 __attribute__((ext_vector_type(4)));

#define SEQ   2048
#define BATCH 4
#define NROWS (BATCH * SEQ)   // 8192
#define DM    1024
#define NH    16
#define HD    64
#define HIDN  4096

__device__ __forceinline__ u16 f2bf(float f) {
  uint32_t u = __builtin_bit_cast(uint32_t, f);
  u += 0x7FFFu + ((u >> 16) & 1u);
  return (u16)(u >> 16);
}

// XOR swizzle for [*][64]-elem bf16 LDS tiles: spreads the 128B row stride
// across banks; 16B-chunk granularity so int4 writes / b128 reads stay intact.
__device__ __forceinline__ int swz(int row, int col) {
  return row * 64 + (((col >> 3) ^ (row & 7)) << 3) + (col & 7);
}

// ---------------------------------------------------------------------------
// fp32 [K][N] -> bf16 [N][K] (B^T layout for GEMM)
__global__ __launch_bounds__(256)
void transpose_w(const float* __restrict__ W, u16* __restrict__ Wt, int K, int N) {
  __shared__ u16 tile[32][33];
  int n0 = blockIdx.x * 32, k0 = blockIdx.y * 32;
  int j = threadIdx.x & 31, i0 = threadIdx.x >> 5;
  #pragma unroll
  for (int i = i0; i < 32; i += 8)
    tile[i][j] = f2bf(W[(size_t)(k0 + i) * N + n0 + j]);
  __syncthreads();
  #pragma unroll
  for (int i = i0; i < 32; i += 8)
    Wt[(size_t)(n0 + i) * K + k0 + j] = tile[j][i];
}

// ---------------------------------------------------------------------------
__global__ __launch_bounds__(256)
void f32_to_bf16_kernel(const float* __restrict__ in, u16* __restrict__ out) {
  size_t i = ((size_t)blockIdx.x * 256 + threadIdx.x) * 8;
  float4 a = *(const float4*)(in + i);
  float4 b = *(const float4*)(in + i + 4);
  int4 v;
  v.x = (int)(f2bf(a.x) | ((uint32_t)f2bf(a.y) << 16));
  v.y = (int)(f2bf(a.z) | ((uint32_t)f2bf(a.w) << 16));
  v.z = (int)(f2bf(b.x) | ((uint32_t)f2bf(b.y) << 16));
  v.w = (int)(f2bf(b.z) | ((uint32_t)f2bf(b.w) << 16));
  *(int4*)(out + i) = v;
}

// ---------------------------------------------------------------------------
// mask int32 [B,S,S] -> u64 bitmask, word j of row r covers kv in [64j,64j+64)
__global__ __launch_bounds__(256)
void mask_bits_kernel(const int* __restrict__ mask, unsigned long long* __restrict__ bits) {
  size_t idx = (size_t)blockIdx.x * 256 + threadIdx.x;
  int m = mask[idx];
  unsigned long long bal = __ballot(m != 0);
  if ((threadIdx.x & 63) == 0) bits[idx >> 6] = bal;
}

// ---------------------------------------------------------------------------
// V bf16 [B*S][NH*HD] -> Vt bf16 [(b*NH+h)*HD + d][SEQ]
__global__ __launch_bounds__(256)
void transpose_v(const u16* __restrict__ V, u16* __restrict__ Vt) {
  int bh = blockIdx.x;           // 0..63
  int st = blockIdx.y;           // 0..31 (s tile of 64)
  int b = bh >> 4, h = bh & 15;
  __shared__ u16 tile[64][65];
  int t = threadIdx.x;
  int sl = t >> 2, c0 = (t & 3) * 16;
  const u16* src = V + (size_t)(b * SEQ + st * 64 + sl) * DM + h * HD + c0;
  int4 va = *(const int4*)(src);
  int4 vb = *(const int4*)(src + 8);
  u16* tr = &tile[sl][c0];
  tr[0] = (u16)va.x; tr[1] = (u16)((uint32_t)va.x >> 16);
  tr[2] = (u16)va.y; tr[3] = (u16)((uint32_t)va.y >> 16);
  tr[4] = (u16)va.z; tr[5] = (u16)((uint32_t)va.z >> 16);
  tr[6] = (u16)va.w; tr[7] = (u16)((uint32_t)va.w >> 16);
  tr[8]  = (u16)vb.x; tr[9]  = (u16)((uint32_t)vb.x >> 16);
  tr[10] = (u16)vb.y; tr[11] = (u16)((uint32_t)vb.y >> 16);
  tr[12] = (u16)vb.z; tr[13] = (u16)((uint32_t)vb.z >> 16);
  tr[14] = (u16)vb.w; tr[15] = (u16)((uint32_t)vb.w >> 16);
  __syncthreads();
  int dl = t >> 2, s0 = (t & 3) * 16;
  uint32_t p[8];
  #pragma unroll
  for (int e = 0; e < 8; ++e)
    p[e] = (uint32_t)tile[s0 + 2*e][dl] | ((uint32_t)tile[s0 + 2*e + 1][dl] << 16);
  u16* dst = Vt + (size_t)(bh * HD + dl) * SEQ + st * 64 + s0;
  int4 o0; o0.x = (int)p[0]; o0.y = (int)p[1]; o0.z = (int)p[2]; o0.w = (int)p[3];
  int4 o1; o1.x = (int)p[4]; o1.y = (int)p[5]; o1.z = (int)p[6]; o1.w = (int)p[7];
  *(int4*)(dst) = o0;
  *(int4*)(dst + 8) = o1;
}

// ---------------------------------------------------------------------------
// GEMM: C[M,N] = A[M,K] (bf16) @ Bt[N,K]^T (bf16), fp32 accumulate.
// EPI: 0 = f32 out, 1 = bf16 out, 2 = +bias f32 out, 3 = +bias relu bf16 out
template <int EPI>
__global__ __launch_bounds__(256)
void gemm_kernel(const u16* __restrict__ A, const u16* __restrict__ Bt,
                 const float* __restrict__ bias, void* __restrict__ Cout,
                 int M, int N, int K) {
  __shared__ __align__(16) u16 As[128 * 64];
  __shared__ __align__(16) u16 Bs[128 * 64];
  const int t = threadIdx.x;
  const int l = t & 63, w = t >> 6;
  const int wm = w >> 1, wn = w & 1;
  const int lg = l >> 4, lr = l & 15;
  const int row0 = blockIdx.x * 128, col0 = blockIdx.y * 128;

  f32x4 acc[4][4];
  #pragma unroll
  for (int i = 0; i < 4; ++i)
    #pragma unroll
    for (int j = 0; j < 4; ++j) acc[i][j] = (f32x4){0.f, 0.f, 0.f, 0.f};

  const int ar = t >> 3, ac = (t & 7) * 8;
  const u16* Agk = A + (size_t)(row0 + ar) * K + ac;
  const u16* Bgk = Bt + (size_t)(col0 + ar) * K + ac;

  const int nk = K >> 6;
  for (int kt = 0; kt < nk; ++kt) {
    int4 av[4], bv[4];
    #pragma unroll
    for (int i = 0; i < 4; ++i) {
      av[i] = *(const int4*)(Agk + (size_t)i * 32 * K + kt * 64);
      bv[i] = *(const int4*)(Bgk + (size_t)i * 32 * K + kt * 64);
    }
    __syncthreads();
    #pragma unroll
    for (int i = 0; i < 4; ++i) {
      *(int4*)&As[swz(ar + i * 32, ac)] = av[i];
      *(int4*)&Bs[swz(ar + i * 32, ac)] = bv[i];
    }
    __syncthreads();
    #pragma unroll
    for (int kx = 0; kx < 2; ++kx) {
      bf16x8 af[4], bf[4];
      #pragma unroll
      for (int mi = 0; mi < 4; ++mi)
        af[mi] = *(const bf16x8*)&As[swz(wm * 64 + mi * 16 + lr, kx * 32 + 8 * lg)];
      #pragma unroll
      for (int ni = 0; ni < 4; ++ni)
        bf[ni] = *(const bf16x8*)&Bs[swz(wn * 64 + ni * 16 + lr, kx * 32 + 8 * lg)];
      #pragma unroll
      for (int mi = 0; mi < 4; ++mi)
        #pragma unroll
        for (int ni = 0; ni < 4; ++ni)
          acc[mi][ni] = __builtin_amdgcn_mfma_f32_16x16x32_bf16(af[mi], bf[ni], acc[mi][ni], 0, 0, 0);
    }
  }

  #pragma unroll
  for (int mi = 0; mi < 4; ++mi) {
    #pragma unroll
    for (int ni = 0; ni < 4; ++ni) {
      int col = col0 + wn * 64 + ni * 16 + lr;
      float badd = (EPI >= 2) ? bias[col] : 0.0f;
      #pragma unroll
      for (int r = 0; r < 4; ++r) {
        int row = row0 + wm * 64 + mi * 16 + 4 * lg + r;
        float v = acc[mi][ni][r] + badd;
        if (EPI == 3) v = fmaxf(v, 0.0f);
        if (EPI == 0 || EPI == 2)
          ((float*)Cout)[(size_t)row * N + col] = v;
        else
          ((u16*)Cout)[(size_t)row * N + col] = f2bf(v);
      }
    }
  }
}

// ---------------------------------------------------------------------------
// Flash attention: grid (S/64 q-tiles, B*NH). 4 waves, 16 q-rows each.
__global__ __launch_bounds__(256)
void attn_kernel(const u16* __restrict__ Q, const u16* __restrict__ Kb,
                 const u16* __restrict__ Vt, const unsigned long long* __restrict__ mbits,
                 u16* __restrict__ Z) {
  const int qt = blockIdx.x;       // 0..31
  const int bh = blockIdx.y;       // 0..63
  const int b = bh >> 4, h = bh & 15;
  const int t = threadIdx.x;
  const int l = t & 63, w = t >> 6;
  const int lg = l >> 4, lr = l & 15;

  __shared__ __align__(16) u16 Ks[64 * 64];
  __shared__ __align__(16) u16 Vs[64 * 64];
  __shared__ __align__(16) u16 Ps[4 * 16 * 64];

  // Q fragments in registers (A-operand: row = lr, k = kx*32 + 8*lg + e)
  const int qrow = qt * 64 + w * 16 + lr;
  const u16* qbase = Q + (size_t)(b * SEQ + qrow) * DM + h * HD;
  bf16x8 qf[2];
  qf[0] = *(const bf16x8*)(qbase + 8 * lg);
  qf[1] = *(const bf16x8*)(qbase + 32 + 8 * lg);

  float m[4], lsum[4];
  f32x4 o[4];
  #pragma unroll
  for (int r = 0; r < 4; ++r) { m[r] = -__builtin_inff(); lsum[r] = 0.f; }
  #pragma unroll
  for (int n = 0; n < 4; ++n) o[n] = (f32x4){0.f, 0.f, 0.f, 0.f};

  const int rr = t >> 3, cc = (t & 7) * 8;
  const u16* Kg = Kb + (size_t)b * SEQ * DM + h * HD + cc;

  for (int kt = 0; kt < SEQ / 64; ++kt) {
    // prefetch to regs
    int4 kreg[2], vreg[2];
    #pragma unroll
    for (int i = 0; i < 2; ++i) {
      kreg[i] = *(const int4*)(Kg + (size_t)(kt * 64 + rr + i * 32) * DM);
      vreg[i] = *(const int4*)(Vt + (size_t)(bh * HD + rr + i * 32) * SEQ + kt * 64 + cc);
    }
    __syncthreads();
    #pragma unroll
    for (int i = 0; i < 2; ++i) {
      *(int4*)&Ks[swz(rr + i * 32, cc)] = kreg[i];   // Ks[kv][d]
      *(int4*)&Vs[swz(rr + i * 32, cc)] = vreg[i];   // Vs[d][kv]
    }
    __syncthreads();

    // S = Q K^T
    f32x4 sc[4];
    #pragma unroll
    for (int n = 0; n < 4; ++n) sc[n] = (f32x4){0.f, 0.f, 0.f, 0.f};
    #pragma unroll
    for (int kx = 0; kx < 2; ++kx) {
      #pragma unroll
      for (int n = 0; n < 4; ++n) {
        bf16x8 kf = *(const bf16x8*)&Ks[swz(n * 16 + lr, kx * 32 + 8 * lg)];
        sc[n] = __builtin_amdgcn_mfma_f32_16x16x32_bf16(qf[kx], kf, sc[n], 0, 0, 0);
      }
    }

    // scale + mask
    unsigned long long mw[4];
    #pragma unroll
    for (int r = 0; r < 4; ++r)
      mw[r] = mbits[((size_t)(b * SEQ) + qt * 64 + w * 16 + 4 * lg + r) * 32 + kt];
    float rowm[4];
    #pragma unroll
    for (int r = 0; r < 4; ++r) rowm[r] = -__builtin_inff();
    #pragma unroll
    for (int n = 0; n < 4; ++n)
      #pragma unroll
      for (int r = 0; r < 4; ++r) {
        float v = sc[n][r] * 0.25f;                       // / sqrt(n_heads)
        v = ((mw[r] >> (n * 16 + lr)) & 1ULL) ? v : -1e9f;
        sc[n][r] = v;
        rowm[r] = fmaxf(rowm[r], v);
      }

    // online softmax (row reduce over the 16 lanes of each lane-group)
    float alpha[4], psum[4];
    #pragma unroll
    for (int r = 0; r < 4; ++r) {
      float rm = rowm[r];
      rm = fmaxf(rm, __shfl_xor(rm, 1));
      rm = fmaxf(rm, __shfl_xor(rm, 2));
      rm = fmaxf(rm, __shfl_xor(rm, 4));
      rm = fmaxf(rm, __shfl_xor(rm, 8));
      float mn = fmaxf(m[r], rm);
      alpha[r] = __expf(m[r] - mn);
      m[r] = mn;
      psum[r] = 0.f;
    }
    #pragma unroll
    for (int n = 0; n < 4; ++n)
      #pragma unroll
      for (int r = 0; r < 4; ++r) {
        float p = __expf(sc[n][r] - m[r]);
        sc[n][r] = p;
        psum[r] += p;
      }
    #pragma unroll
    for (int r = 0; r < 4; ++r) {
      float ps = psum[r];
      ps += __shfl_xor(ps, 1);
      ps += __shfl_xor(ps, 2);
      ps += __shfl_xor(ps, 4);
      ps += __shfl_xor(ps, 8);
      lsum[r] = lsum[r] * alpha[r] + ps;
      #pragma unroll
      for (int n = 0; n < 4; ++n) o[n][r] *= alpha[r];
    }

    // P -> LDS (per-wave region), reshape into A-fragment layout
    #pragma unroll
    for (int n = 0; n < 4; ++n)
      #pragma unroll
      for (int r = 0; r < 4; ++r)
        Ps[w * 1024 + swz(4 * lg + r, n * 16 + lr)] = f2bf(sc[n][r]);
    asm volatile("s_waitcnt lgkmcnt(0)" ::: "memory");

    // O += P V
    #pragma unroll
    for (int kx = 0; kx < 2; ++kx) {
      bf16x8 pf = *(const bf16x8*)&Ps[w * 1024 + swz(lr, kx * 32 + 8 * lg)];
      #pragma unroll
      for (int n = 0; n < 4; ++n) {
        bf16x8 vf = *(const bf16x8*)&Vs[swz(n * 16 + lr, kx * 32 + 8 * lg)];
        o[n] = __builtin_amdgcn_mfma_f32_16x16x32_bf16(pf, vf, o[n], 0, 0, 0);
      }
    }
  }

  #pragma unroll
  for (int n = 0; n < 4; ++n)
    #pragma unroll
    for (int r = 0; r < 4; ++r) {
      int qg = qt * 64 + w * 16 + 4 * lg + r;
      float val = o[n][r] / lsum[r];
      Z[((size_t)(b * SEQ) + qg) * DM + h * HD + n * 16 + lr] = f2bf(val);
    }
}

// ---------------------------------------------------------------------------
// out = LN(a + res); optionally also bf16 copy
__global__ __launch_bounds__(256)
void ln_kernel(const float* __restrict__ a, const float* __restrict__ res,
               const float* __restrict__ g, const float* __restrict__ be,
               float* __restrict__ of, u16* __restrict__ ob) {
  int row = blockIdx.x;
  int t = threadIdx.x, l = t & 63, w = t >> 6;
  float4 va = *(const float4*)(a + (size_t)row * DM + t * 4);
  float4 vr = *(const float4*)(res + (size_t)row * DM + t * 4);
  float v0 = va.x + vr.x, v1 = va.y + vr.y, v2 = va.z + vr.z, v3 = va.w + vr.w;
  float s = v0 + v1 + v2 + v3;
  #pragma unroll
  for (int off = 32; off >= 1; off >>= 1) s += __shfl_xor(s, off);
  __shared__ float red[8];
  if (l == 0) red[w] = s;
  __syncthreads();
  float mean = (red[0] + red[1] + red[2] + red[3]) * (1.0f / DM);
  float d0 = v0 - mean, d1 = v1 - mean, d2 = v2 - mean, d3 = v3 - mean;
  float q = d0 * d0 + d1 * d1 + d2 * d2 + d3 * d3;
  #pragma unroll
  for (int off = 32; off >= 1; off >>= 1) q += __shfl_xor(q, off);
  if (l == 0) red[4 + w] = q;
  __syncthreads();
  float var = (red[4] + red[5] + red[6] + red[7]) * (1.0f / DM);
  float rstd = rsqrtf(var + 1e-5f);
  float4 gv = *(const float4*)(g + t * 4);
  float4 bv = *(const float4*)(be + t * 4);
  float o0 = d0 * rstd * gv.x + bv.x;
  float o1 = d1 * rstd * gv.y + bv.y;
  float o2 = d2 * rstd * gv.z + bv.z;
  float o3 = d3 * rstd * gv.w + bv.w;
  float4 ov; ov.x = o0; ov.y = o1; ov.z = o2; ov.w = o3;
  *(float4*)(of + (size_t)row * DM + t * 4) = ov;
  if (ob) {
    uint2 pv;
    pv.x = f2bf(o0) | ((uint32_t)f2bf(o1) << 16);
    pv.y = f2bf(o2) | ((uint32_t)f2bf(o3) << 16);
    *(uint2*)(ob + (size_t)row * DM + t * 4) = pv;
  }
}

// ---------------------------------------------------------------------------
extern "C" void kernel_launch(void* const* d_in, const int* in_sizes, int n_in,
                              void* d_out, int out_size, void* d_ws, size_t ws_size,
                              hipStream_t stream) {
  (void)in_sizes; (void)n_in; (void)out_size; (void)ws_size;
  const float* x    = (const float*)d_in[0];
  const int*   mask = (const int*)d_in[1];
  const float* Wq   = (const float*)d_in[2];
  const float* Wk   = (const float*)d_in[3];
  const float* Wv   = (const float*)d_in[4];
  const float* Wo   = (const float*)d_in[5];
  const float* ln1g = (const float*)d_in[6];
  const float* ln1b = (const float*)d_in[7];
  const float* W1   = (const float*)d_in[8];
  const float* b1   = (const float*)d_in[9];
  const float* W2   = (const float*)d_in[10];
  const float* b2   = (const float*)d_in[11];
  const float* ln2g = (const float*)d_in[12];
  const float* ln2b = (const float*)d_in[13];
  float* out = (float*)d_out;

  char* ws = (char*)d_ws;
  const size_t MB = 1024 * 1024;
  u16* WqT = (u16*)(ws + 0 * MB);      // 2MB
  u16* WkT = (u16*)(ws + 2 * MB);      // 2MB
  u16* WvT = (u16*)(ws + 4 * MB);      // 2MB
  u16* WoT = (u16*)(ws + 6 * MB);      // 2MB
  u16* W1T = (u16*)(ws + 8 * MB);      // 8MB [4096][1024]
  u16* W2T = (u16*)(ws + 16 * MB);     // 8MB [1024][4096]
  u16* Xb  = (u16*)(ws + 24 * MB);     // 16MB ; aliased by Z after QKV
  u16* Qb  = (u16*)(ws + 40 * MB);     // 16MB ; h_f32 spans 40..72 later
  u16* Kb  = (u16*)(ws + 56 * MB);     // 16MB
  u16* Vb  = (u16*)(ws + 72 * MB);     // 16MB ; h_b16 later
  u16* Vt  = (u16*)(ws + 88 * MB);     // 16MB
  unsigned long long* mbits = (unsigned long long*)(ws + 104 * MB);  // 2MB
  float* attn_out = (float*)(ws + 106 * MB);  // 32MB ; ff2 later
  u16* ff1 = (u16*)(ws + 138 * MB);    // 64MB  -> total 202MB
  float* h_f32 = (float*)(ws + 40 * MB);
  u16*   h_b16 = (u16*)(ws + 72 * MB);
  u16*   Z     = Xb;
  float* ff2   = attn_out;

  dim3 tb(256);
  transpose_w<<<dim3(32, 32), tb, 0, stream>>>(Wq, WqT, DM, DM);
  transpose_w<<<dim3(32, 32), tb, 0, stream>>>(Wk, WkT, DM, DM);
  transpose_w<<<dim3(32, 32), tb, 0, stream>>>(Wv, WvT, DM, DM);
  transpose_w<<<dim3(32, 32), tb, 0, stream>>>(Wo, WoT, DM, DM);
  transpose_w<<<dim3(128, 32), tb, 0, stream>>>(W1, W1T, DM, HIDN);
  transpose_w<<<dim3(32, 128), tb, 0, stream>>>(W2, W2T, HIDN, DM);

  f32_to_bf16_kernel<<<(NROWS * DM) / (256 * 8), tb, 0, stream>>>(x, Xb);
  mask_bits_kernel<<<(BATCH * SEQ * SEQ) / 256, tb, 0, stream>>>(mask, mbits);

  gemm_kernel<1><<<dim3(64, 8), tb, 0, stream>>>(Xb, WqT, nullptr, Qb, NROWS, DM, DM);
  gemm_kernel<1><<<dim3(64, 8), tb, 0, stream>>>(Xb, WkT, nullptr, Kb, NROWS, DM, DM);
  gemm_kernel<1><<<dim3(64, 8), tb, 0, stream>>>(Xb, WvT, nullptr, Vb, NROWS, DM, DM);
  transpose_v<<<dim3(64, 32), tb, 0, stream>>>(Vb, Vt);

  attn_kernel<<<dim3(32, 64), tb, 0, stream>>>(Qb, Kb, Vt, mbits, Z);

  gemm_kernel<0><<<dim3(64, 8), tb, 0, stream>>>(Z, WoT, nullptr, attn_out, NROWS, DM, DM);
  ln_kernel<<<NROWS, tb, 0, stream>>>(attn_out, x, ln1g, ln1b, h_f32, h_b16);
  gemm_kernel<3><<<dim3(64, 32), tb, 0, stream>>>(h_b16, W1T, b1, ff1, NROWS, HIDN, DM);
  gemm_kernel<2><<<dim3(64, 8), tb, 0, stream>>>(ff1, W2T, b2, ff2, NROWS, DM, HIDN);
  ln_kernel<<<NROWS, tb, 0, stream>>>(ff2, h_f32, ln2g, ln2b, out, nullptr);
}

// Round 3
// 824.376 us; speedup vs baseline: 1.9646x; 1.9646x over previous
//
#include <hip/hip_runtime.h>
#include <stdint.h>

typedef uint16_t u16;
typedef short bf16x8 __attribute__((ext_vector_type(8)));
typedef float f32x4 __attribute__((ext_vector_type(4)));

#define SEQ   2048
#define BATCH 4
#define NROWS (BATCH * SEQ)   // 8192
#define DM    1024
#define NH    16
#define HD    64
#define HIDN  4096
#define KVB   128

__device__ __forceinline__ u16 f2bf(float f) {
  uint32_t u = __builtin_bit_cast(uint32_t, f);
  u += 0x7FFFu + ((u >> 16) & 1u);
  return (u16)(u >> 16);
}

// async global->LDS, 16B per lane; LDS dest = wave-uniform base + lane*16
__device__ __forceinline__ void gl16(const void* g, void* l) {
  __builtin_amdgcn_global_load_lds(
      (const __attribute__((address_space(1))) void*)g,
      (__attribute__((address_space(3))) void*)l, 16, 0, 0);
}

// XOR swizzle for P tile [16][128] u16 (16B chunk granularity)
__device__ __forceinline__ int swzP(int row, int col) {
  return row * 128 + ((((col >> 3) ^ (row & 7))) << 3) + (col & 7);
}

// ---------------------------------------------------------------------------
// fp32 [K][N] -> bf16 [N][K] (B^T layout for GEMM)
__global__ __launch_bounds__(256)
void transpose_w(const float* __restrict__ W, u16* __restrict__ Wt, int K, int N) {
  __shared__ u16 tile[32][33];
  int n0 = blockIdx.x * 32, k0 = blockIdx.y * 32;
  int j = threadIdx.x & 31, i0 = threadIdx.x >> 5;
  #pragma unroll
  for (int i = i0; i < 32; i += 8)
    tile[i][j] = f2bf(W[(size_t)(k0 + i) * N + n0 + j]);
  __syncthreads();
  #pragma unroll
  for (int i = i0; i < 32; i += 8)
    Wt[(size_t)(n0 + i) * K + k0 + j] = tile[j][i];
}

// ---------------------------------------------------------------------------
__global__ __launch_bounds__(256)
void f32_to_bf16_kernel(const float* __restrict__ in, u16* __restrict__ out) {
  size_t i = ((size_t)blockIdx.x * 256 + threadIdx.x) * 8;
  float4 a = *(const float4*)(in + i);
  float4 b = *(const float4*)(in + i + 4);
  int4 v;
  v.x = (int)(f2bf(a.x) | ((uint32_t)f2bf(a.y) << 16));
  v.y = (int)(f2bf(a.z) | ((uint32_t)f2bf(a.w) << 16));
  v.z = (int)(f2bf(b.x) | ((uint32_t)f2bf(b.y) << 16));
  v.w = (int)(f2bf(b.z) | ((uint32_t)f2bf(b.w) << 16));
  *(int4*)(out + i) = v;
}

// ---------------------------------------------------------------------------
// flags[row*16 + t128] = 1 iff mask[row][t128*128 .. +128) all nonzero
__global__ __launch_bounds__(256)
void mask_flags_kernel(const int* __restrict__ mask, unsigned char* __restrict__ flags) {
  size_t row = blockIdx.x;            // b*SEQ + q
  int t = threadIdx.x;
  int t128 = t >> 4, sub = t & 15;
  const int* p = mask + row * SEQ + t128 * 128 + sub * 8;
  int4 a = *(const int4*)p;
  int4 c = *(const int4*)(p + 4);
  int ok = (a.x && a.y && a.z && a.w && c.x && c.y && c.z && c.w) ? 1 : 0;
  ok &= __shfl_xor(ok, 1);
  ok &= __shfl_xor(ok, 2);
  ok &= __shfl_xor(ok, 4);
  ok &= __shfl_xor(ok, 8);
  if (sub == 0) flags[row * 16 + t128] = (unsigned char)ok;
}

// ---------------------------------------------------------------------------
// V slice of QKV [B*S][3072] (cols 2048..3071) -> Vt bf16 [(b*NH+h)*HD + d][SEQ]
__global__ __launch_bounds__(256)
void transpose_v(const u16* __restrict__ QKV, u16* __restrict__ Vt) {
  int bh = blockIdx.x;           // 0..63
  int st = blockIdx.y;           // 0..31 (s tile of 64)
  int b = bh >> 4, h = bh & 15;
  __shared__ u16 tile[64][65];
  int t = threadIdx.x;
  int sl = t >> 2, c0 = (t & 3) * 16;
  const u16* src = QKV + (size_t)(b * SEQ + st * 64 + sl) * 3072 + 2048 + h * HD + c0;
  int4 va = *(const int4*)(src);
  int4 vb = *(const int4*)(src + 8);
  u16* tr = &tile[sl][c0];
  tr[0] = (u16)va.x; tr[1] = (u16)((uint32_t)va.x >> 16);
  tr[2] = (u16)va.y; tr[3] = (u16)((uint32_t)va.y >> 16);
  tr[4] = (u16)va.z; tr[5] = (u16)((uint32_t)va.z >> 16);
  tr[6] = (u16)va.w; tr[7] = (u16)((uint32_t)va.w >> 16);
  tr[8]  = (u16)vb.x; tr[9]  = (u16)((uint32_t)vb.x >> 16);
  tr[10] = (u16)vb.y; tr[11] = (u16)((uint32_t)vb.y >> 16);
  tr[12] = (u16)vb.z; tr[13] = (u16)((uint32_t)vb.z >> 16);
  tr[14] = (u16)vb.w; tr[15] = (u16)((uint32_t)vb.w >> 16);
  __syncthreads();
  int dl = t >> 2, s0 = (t & 3) * 16;
  uint32_t p[8];
  #pragma unroll
  for (int e = 0; e < 8; ++e)
    p[e] = (uint32_t)tile[s0 + 2*e][dl] | ((uint32_t)tile[s0 + 2*e + 1][dl] << 16);
  u16* dst = Vt + (size_t)(bh * HD + dl) * SEQ + st * 64 + s0;
  int4 o0; o0.x = (int)p[0]; o0.y = (int)p[1]; o0.z = (int)p[2]; o0.w = (int)p[3];
  int4 o1; o1.x = (int)p[4]; o1.y = (int)p[5]; o1.z = (int)p[6]; o1.w = (int)p[7];
  *(int4*)(dst) = o0;
  *(int4*)(dst + 8) = o1;
}

// ---------------------------------------------------------------------------
// GEMM (m97 structure): C[M,N] = A[M,K] bf16 @ Bt[N,K]^T bf16, fp32 acc.
// Linear LDS + global_load_lds width-16 staging.
// EPI: 0 = f32 out, 1 = bf16 out, 2 = +bias f32 out, 3 = +bias relu bf16 out
template <int EPI>
__global__ __launch_bounds__(256, 2)
void gemm_kernel(const u16* __restrict__ A, const u16* __restrict__ Bt,
                 const float* __restrict__ bias, void* __restrict__ Cout,
                 int M, int N, int K) {
  __shared__ __align__(16) u16 As[128 * 64];
  __shared__ __align__(16) u16 Bs[128 * 64];
  const int t = threadIdx.x;
  const int l = t & 63, w = t >> 6;
  const int wm = w >> 1, wn = w & 1;
  const int lg = l >> 4, lr = l & 15;
  const int row0 = blockIdx.x * 128, col0 = blockIdx.y * 128;

  f32x4 acc[4][4];
  #pragma unroll
  for (int i = 0; i < 4; ++i)
    #pragma unroll
    for (int j = 0; j < 4; ++j) acc[i][j] = (f32x4){0.f, 0.f, 0.f, 0.f};

  // staging addresses: wave w covers rows [w*32, w*32+32) of each tile;
  // 8 lanes per 128B row, 8 rows per 1KB instruction
  const int srow = w * 32 + (l >> 3);
  const int scol = (l & 7) * 8;
  const u16* Ag = A + (size_t)(row0 + srow) * K + scol;
  const u16* Bg = Bt + (size_t)(col0 + srow) * K + scol;

  const int nk = K >> 6;
  // prologue: stage tile 0
  #pragma unroll
  for (int i = 0; i < 4; ++i) {
    gl16(Ag + (size_t)i * 8 * K, &As[(w * 32 + i * 8) * 64]);
    gl16(Bg + (size_t)i * 8 * K, &Bs[(w * 32 + i * 8) * 64]);
  }
  for (int kt = 0; kt < nk; ++kt) {
    __syncthreads();   // drains own vmcnt -> tile kt staged, all waves synced
    #pragma unroll
    for (int kx = 0; kx < 2; ++kx) {
      bf16x8 af[4], bf[4];
      #pragma unroll
      for (int mi = 0; mi < 4; ++mi)
        af[mi] = *(const bf16x8*)&As[(wm * 64 + mi * 16 + lr) * 64 + kx * 32 + 8 * lg];
      #pragma unroll
      for (int ni = 0; ni < 4; ++ni)
        bf[ni] = *(const bf16x8*)&Bs[(wn * 64 + ni * 16 + lr) * 64 + kx * 32 + 8 * lg];
      #pragma unroll
      for (int mi = 0; mi < 4; ++mi)
        #pragma unroll
        for (int ni = 0; ni < 4; ++ni)
          acc[mi][ni] = __builtin_amdgcn_mfma_f32_16x16x32_bf16(af[mi], bf[ni], acc[mi][ni], 0, 0, 0);
    }
    __syncthreads();   // all waves done reading before overwrite
    if (kt + 1 < nk) {
      #pragma unroll
      for (int i = 0; i < 4; ++i) {
        gl16(Ag + (size_t)((kt + 1) * 64) + (size_t)i * 8 * K, &As[(w * 32 + i * 8) * 64]);
        gl16(Bg + (size_t)((kt + 1) * 64) + (size_t)i * 8 * K, &Bs[(w * 32 + i * 8) * 64]);
      }
    }
  }

  #pragma unroll
  for (int mi = 0; mi < 4; ++mi) {
    #pragma unroll
    for (int ni = 0; ni < 4; ++ni) {
      int col = col0 + wn * 64 + ni * 16 + lr;
      float badd = (EPI >= 2) ? bias[col] : 0.0f;
      #pragma unroll
      for (int r = 0; r < 4; ++r) {
        int row = row0 + wm * 64 + mi * 16 + 4 * lg + r;
        float v = acc[mi][ni][r] + badd;
        if (EPI == 3) v = fmaxf(v, 0.0f);
        if (EPI == 0 || EPI == 2)
          ((float*)Cout)[(size_t)row * N + col] = v;
        else
          ((u16*)Cout)[(size_t)row * N + col] = f2bf(v);
      }
    }
  }
}

// ---------------------------------------------------------------------------
// Flash attention: grid (S/64 q-tiles, B*NH). 4 waves, 16 q-rows each.
// KV tiles of 128, double-buffered K/V in LDS via global_load_lds,
// counted vmcnt(8) + raw barriers (2-phase pipeline).
__global__ __launch_bounds__(256, 2)
void attn_kernel(const u16* __restrict__ QKV, const u16* __restrict__ Vt,
                 const int* __restrict__ mask, const unsigned char* __restrict__ flags,
                 u16* __restrict__ Z) {
  const int qt = blockIdx.x;       // 0..31
  const int bh = blockIdx.y;       // 0..63
  const int b = bh >> 4, h = bh & 15;
  const int t = threadIdx.x;
  const int l = t & 63, w = t >> 6;
  const int lg = l >> 4, lr = l & 15;

  __shared__ __align__(16) u16 Ks[2][KVB * 64];   // [kv][d], linear
  __shared__ __align__(16) u16 Vs[2][64 * KVB];   // [d][kv], linear
  __shared__ __align__(16) u16 Ps[4][16 * KVB];   // per-wave P, swizzled

  // Q fragments (A-operand: row = lr = q, k = kx*32 + 8*lg + e)
  const int qrow = qt * 64 + w * 16 + lr;
  const u16* qb = QKV + (size_t)(b * SEQ + qrow) * 3072 + h * HD;
  bf16x8 qf[2];
  qf[0] = *(const bf16x8*)(qb + 8 * lg);
  qf[1] = *(const bf16x8*)(qb + 32 + 8 * lg);

  float m[4], lsum[4];
  f32x4 o[4];
  #pragma unroll
  for (int r = 0; r < 4; ++r) { m[r] = -__builtin_inff(); lsum[r] = 0.f; }
  #pragma unroll
  for (int n = 0; n < 4; ++n) o[n] = (f32x4){0.f, 0.f, 0.f, 0.f};

  // staging source bases
  const u16* Kg = QKV + (size_t)(b * SEQ) * 3072 + 1024 + h * HD;   // + row*3072
  const u16* Vg = Vt + (size_t)(bh * HD) * SEQ;                      // + d*SEQ
  const int k_r = w * 32 + (l >> 3), k_c = (l & 7) * 8;   // K: 8 lanes/row
  const int v_r = w * 16 + (l >> 4), v_c = (l & 15) * 8;  // V: 16 lanes/row
  u16* ps = &Ps[w][0];

  #define STAGE(kt_, buf_)                                                     \
    {                                                                          \
      _Pragma("unroll")                                                        \
      for (int i = 0; i < 4; ++i)                                              \
        gl16(Kg + (size_t)((kt_) * KVB + k_r + i * 8) * 3072 + k_c,            \
             &Ks[buf_][(w * 32 + i * 8) * 64]);                                \
      _Pragma("unroll")                                                        \
      for (int i = 0; i < 4; ++i)                                              \
        gl16(Vg + (size_t)(v_r + i * 4) * SEQ + (kt_) * KVB + v_c,             \
             &Vs[buf_][(w * 16 + i * 4) * KVB]);                               \
    }

  STAGE(0, 0);
  const int NT = SEQ / KVB;   // 16
  for (int kt = 0; kt < NT; ++kt) {
    const int cb = kt & 1;
    STAGE((kt + 1) & (NT - 1), cb ^ 1);   // prefetch next (wraps harmlessly)
    __builtin_amdgcn_sched_barrier(0);
    asm volatile("s_waitcnt vmcnt(8)" ::: "memory");   // current tile landed
    __builtin_amdgcn_sched_barrier(0);
    __builtin_amdgcn_s_barrier();

    const u16* ks = &Ks[cb][0];
    const u16* vs = &Vs[cb][0];

    // S = Q K^T  -> sc[n] covers kv = n*16 + lr, q-rows 4*lg+r
    f32x4 sc[8];
    #pragma unroll
    for (int n = 0; n < 8; ++n) sc[n] = (f32x4){0.f, 0.f, 0.f, 0.f};
    #pragma unroll
    for (int kx = 0; kx < 2; ++kx)
      #pragma unroll
      for (int n = 0; n < 8; ++n) {
        bf16x8 kf = *(const bf16x8*)&ks[(n * 16 + lr) * 64 + kx * 32 + 8 * lg];
        sc[n] = __builtin_amdgcn_mfma_f32_16x16x32_bf16(qf[kx], kf, sc[n], 0, 0, 0);
      }

    // mask fast path: per-row all-ones flag for this 128-tile
    const unsigned char* fb = flags + ((size_t)(b * SEQ) + qt * 64 + w * 16 + 4 * lg) * 16 + kt;
    int allin = fb[0] & fb[16] & fb[32] & fb[48];
    float rowm[4];
    #pragma unroll
    for (int r = 0; r < 4; ++r) rowm[r] = -__builtin_inff();
    if (__all(allin != 0)) {
      #pragma unroll
      for (int n = 0; n < 8; ++n)
        #pragma unroll
        for (int r = 0; r < 4; ++r) {
          float v = sc[n][r] * 0.25f;   // / sqrt(n_heads)
          sc[n][r] = v;
          rowm[r] = fmaxf(rowm[r], v);
        }
    } else {
      const int* mrow = mask + ((size_t)(b * SEQ) + qt * 64 + w * 16 + 4 * lg) * SEQ
                        + (size_t)kt * KVB + lr;
      #pragma unroll
      for (int n = 0; n < 8; ++n)
        #pragma unroll
        for (int r = 0; r < 4; ++r) {
          int mv = mrow[(size_t)r * SEQ + n * 16];
          float v = sc[n][r] * 0.25f;
          v = mv ? v : -1e9f;
          sc[n][r] = v;
          rowm[r] = fmaxf(rowm[r], v);
        }
    }

    // online softmax (reduce over 16 lanes sharing a q-row)
    float alpha[4], psum[4];
    #pragma unroll
    for (int r = 0; r < 4; ++r) {
      float rm = rowm[r];
      rm = fmaxf(rm, __shfl_xor(rm, 1));
      rm = fmaxf(rm, __shfl_xor(rm, 2));
      rm = fmaxf(rm, __shfl_xor(rm, 4));
      rm = fmaxf(rm, __shfl_xor(rm, 8));
      float mn = fmaxf(m[r], rm);
      alpha[r] = __expf(m[r] - mn);
      m[r] = mn;
      psum[r] = 0.f;
    }
    #pragma unroll
    for (int n = 0; n < 8; ++n)
      #pragma unroll
      for (int r = 0; r < 4; ++r) {
        float p = __expf(sc[n][r] - m[r]);
        sc[n][r] = p;
        psum[r] += p;
      }
    #pragma unroll
    for (int r = 0; r < 4; ++r) {
      float ps_ = psum[r];
      ps_ += __shfl_xor(ps_, 1);
      ps_ += __shfl_xor(ps_, 2);
      ps_ += __shfl_xor(ps_, 4);
      ps_ += __shfl_xor(ps_, 8);
      lsum[r] = lsum[r] * alpha[r] + ps_;
      #pragma unroll
      for (int n = 0; n < 4; ++n) o[n][r] *= alpha[r];
    }

    // P -> per-wave LDS (reshape C-layout -> A-fragment layout)
    #pragma unroll
    for (int n = 0; n < 8; ++n)
      #pragma unroll
      for (int r = 0; r < 4; ++r)
        ps[swzP(4 * lg + r, n * 16 + lr)] = f2bf(sc[n][r]);
    asm volatile("s_waitcnt lgkmcnt(0)" ::: "memory");
    __builtin_amdgcn_sched_barrier(0);

    // O += P V   (A = P[q][kv], B = V^T[d][kv] read as B[kv][d])
    #pragma unroll
    for (int kx = 0; kx < 4; ++kx) {
      bf16x8 pf = *(const bf16x8*)&ps[swzP(lr, kx * 32 + 8 * lg)];
      #pragma unroll
      for (int n = 0; n < 4; ++n) {
        bf16x8 vf = *(const bf16x8*)&vs[(n * 16 + lr) * KVB + kx * 32 + 8 * lg];
        o[n] = __builtin_amdgcn_mfma_f32_16x16x32_bf16(pf, vf, o[n], 0, 0, 0);
      }
    }
    __builtin_amdgcn_sched_barrier(0);
    __builtin_amdgcn_s_barrier();   // all waves done reading Ks/Vs[cb]
  }
  #undef STAGE

  #pragma unroll
  for (int n = 0; n < 4; ++n)
    #pragma unroll
    for (int r = 0; r < 4; ++r) {
      int qg = qt * 64 + w * 16 + 4 * lg + r;
      float val = o[n][r] / lsum[r];
      Z[((size_t)(b * SEQ) + qg) * DM + h * HD + n * 16 + lr] = f2bf(val);
    }
}

// ---------------------------------------------------------------------------
// out = LN(a + res); optionally also bf16 copy
__global__ __launch_bounds__(256)
void ln_kernel(const float* __restrict__ a, const float* __restrict__ res,
               const float* __restrict__ g, const float* __restrict__ be,
               float* __restrict__ of, u16* __restrict__ ob) {
  int row = blockIdx.x;
  int t = threadIdx.x, l = t & 63, w = t >> 6;
  float4 va = *(const float4*)(a + (size_t)row * DM + t * 4);
  float4 vr = *(const float4*)(res + (size_t)row * DM + t * 4);
  float v0 = va.x + vr.x, v1 = va.y + vr.y, v2 = va.z + vr.z, v3 = va.w + vr.w;
  float s = v0 + v1 + v2 + v3;
  #pragma unroll
  for (int off = 32; off >= 1; off >>= 1) s += __shfl_xor(s, off);
  __shared__ float red[8];
  if (l == 0) red[w] = s;
  __syncthreads();
  float mean = (red[0] + red[1] + red[2] + red[3]) * (1.0f / DM);
  float d0 = v0 - mean, d1 = v1 - mean, d2 = v2 - mean, d3 = v3 - mean;
  float q = d0 * d0 + d1 * d1 + d2 * d2 + d3 * d3;
  #pragma unroll
  for (int off = 32; off >= 1; off >>= 1) q += __shfl_xor(q, off);
  if (l == 0) red[4 + w] = q;
  __syncthreads();
  float var = (red[4] + red[5] + red[6] + red[7]) * (1.0f / DM);
  float rstd = rsqrtf(var + 1e-5f);
  float4 gv = *(const float4*)(g + t * 4);
  float4 bv = *(const float4*)(be + t * 4);
  float o0 = d0 * rstd * gv.x + bv.x;
  float o1 = d1 * rstd * gv.y + bv.y;
  float o2 = d2 * rstd * gv.z + bv.z;
  float o3 = d3 * rstd * gv.w + bv.w;
  float4 ov; ov.x = o0; ov.y = o1; ov.z = o2; ov.w = o3;
  *(float4*)(of + (size_t)row * DM + t * 4) = ov;
  if (ob) {
    uint2 pv;
    pv.x = f2bf(o0) | ((uint32_t)f2bf(o1) << 16);
    pv.y = f2bf(o2) | ((uint32_t)f2bf(o3) << 16);
    *(uint2*)(ob + (size_t)row * DM + t * 4) = pv;
  }
}

// ---------------------------------------------------------------------------
extern "C" void kernel_launch(void* const* d_in, const int* in_sizes, int n_in,
                              void* d_out, int out_size, void* d_ws, size_t ws_size,
                              hipStream_t stream) {
  (void)in_sizes; (void)n_in; (void)out_size; (void)ws_size;
  const float* x    = (const float*)d_in[0];
  const int*   mask = (const int*)d_in[1];
  const float* Wq   = (const float*)d_in[2];
  const float* Wk   = (const float*)d_in[3];
  const float* Wv   = (const float*)d_in[4];
  const float* Wo   = (const float*)d_in[5];
  const float* ln1g = (const float*)d_in[6];
  const float* ln1b = (const float*)d_in[7];
  const float* W1   = (const float*)d_in[8];
  const float* b1   = (const float*)d_in[9];
  const float* W2   = (const float*)d_in[10];
  const float* b2   = (const float*)d_in[11];
  const float* ln2g = (const float*)d_in[12];
  const float* ln2b = (const float*)d_in[13];
  float* out = (float*)d_out;

  char* ws = (char*)d_ws;
  const size_t MB = 1024 * 1024;
  u16* WqkvT = (u16*)(ws + 0 * MB);     // 6MB: Wq^T | Wk^T | Wv^T rows
  u16* WoT   = (u16*)(ws + 6 * MB);     // 2MB
  u16* W1T   = (u16*)(ws + 8 * MB);     // 8MB [4096][1024]
  u16* W2T   = (u16*)(ws + 16 * MB);    // 8MB [1024][4096]
  u16* Xb    = (u16*)(ws + 24 * MB);    // 16MB ; Z aliases after QKV gemm
  u16* QKV   = (u16*)(ws + 40 * MB);    // 48MB [8192][3072]
  u16* Vt    = (u16*)(ws + 88 * MB);    // 16MB
  unsigned char* flags = (unsigned char*)(ws + 104 * MB);  // 128KB
  float* attn_out = (float*)(ws + 105 * MB);  // 32MB ; ff2 aliases
  u16* ff1   = (u16*)(ws + 137 * MB);   // 64MB -> total 201MB
  float* h_f32 = (float*)(ws + 40 * MB);   // over QKV (dead after attn)
  u16*   h_b16 = (u16*)(ws + 72 * MB);     // over QKV tail
  u16*   Z     = Xb;                        // attn output
  float* ff2   = attn_out;

  dim3 tb(256);
  transpose_w<<<dim3(32, 32), tb, 0, stream>>>(Wq, WqkvT, DM, DM);
  transpose_w<<<dim3(32, 32), tb, 0, stream>>>(Wk, WqkvT + (size_t)1024 * 1024, DM, DM);
  transpose_w<<<dim3(32, 32), tb, 0, stream>>>(Wv, WqkvT + (size_t)2048 * 1024, DM, DM);
  transpose_w<<<dim3(32, 32), tb, 0, stream>>>(Wo, WoT, DM, DM);
  transpose_w<<<dim3(128, 32), tb, 0, stream>>>(W1, W1T, DM, HIDN);
  transpose_w<<<dim3(32, 128), tb, 0, stream>>>(W2, W2T, HIDN, DM);

  f32_to_bf16_kernel<<<(NROWS * DM) / (256 * 8), tb, 0, stream>>>(x, Xb);
  mask_flags_kernel<<<NROWS, tb, 0, stream>>>(mask, flags);

  // fused QKV projection: [8192,1024] @ [1024,3072]
  gemm_kernel<1><<<dim3(64, 24), tb, 0, stream>>>(Xb, WqkvT, nullptr, QKV, NROWS, 3072, DM);
  transpose_v<<<dim3(64, 32), tb, 0, stream>>>(QKV, Vt);

  attn_kernel<<<dim3(32, 64), tb, 0, stream>>>(QKV, Vt, mask, flags, Z);

  gemm_kernel<0><<<dim3(64, 8), tb, 0, stream>>>(Z, WoT, nullptr, attn_out, NROWS, DM, DM);
  ln_kernel<<<NROWS, tb, 0, stream>>>(attn_out, x, ln1g, ln1b, h_f32, h_b16);
  gemm_kernel<3><<<dim3(64, 32), tb, 0, stream>>>(h_b16, W1T, b1, ff1, NROWS, HIDN, DM);
  gemm_kernel<2><<<dim3(64, 8), tb, 0, stream>>>(ff1, W2T, b2, ff2, NROWS, DM, HIDN);
  ln_kernel<<<NROWS, tb, 0, stream>>>(ff2, h_f32, ln2g, ln2b, out, nullptr);
}

// Round 4
// 724.416 us; speedup vs baseline: 2.2357x; 1.1380x over previous
//
#include <hip/hip_runtime.h>
#include <stdint.h>

typedef uint16_t u16;
typedef short bf16x8 __attribute__((ext_vector_type(8)));
typedef float f32x4 __attribute__((ext_vector_type(4)));

#define SEQ   2048
#define BATCH 4
#define NROWS (BATCH * SEQ)   // 8192
#define DM    1024
#define NH    16
#define HD    64
#define HIDN  4096
#define KVB   128

__device__ __forceinline__ u16 f2bf(float f) {
  uint32_t u = __builtin_bit_cast(uint32_t, f);
  u += 0x7FFFu + ((u >> 16) & 1u);
  return (u16)(u >> 16);
}

// async global->LDS, 16B per lane; LDS dest = wave-uniform base + lane*16
__device__ __forceinline__ void gl16(const void* g, void* l) {
  __builtin_amdgcn_global_load_lds(
      (const __attribute__((address_space(1))) void*)g,
      (__attribute__((address_space(3))) void*)l, 16, 0, 0);
}

// XOR swizzle for P tile [16][128] u16 (16B chunk granularity)
__device__ __forceinline__ int swzP(int row, int col) {
  return row * 128 + ((((col >> 3) ^ (row & 7))) << 3) + (col & 7);
}

// ---------------------------------------------------------------------------
// fp32 [K][N] -> bf16 [N][K] (B^T layout for GEMM)
__global__ __launch_bounds__(256)
void transpose_w(const float* __restrict__ W, u16* __restrict__ Wt, int K, int N) {
  __shared__ u16 tile[32][33];
  int n0 = blockIdx.x * 32, k0 = blockIdx.y * 32;
  int j = threadIdx.x & 31, i0 = threadIdx.x >> 5;
  #pragma unroll
  for (int i = i0; i < 32; i += 8)
    tile[i][j] = f2bf(W[(size_t)(k0 + i) * N + n0 + j]);
  __syncthreads();
  #pragma unroll
  for (int i = i0; i < 32; i += 8)
    Wt[(size_t)(n0 + i) * K + k0 + j] = tile[j][i];
}

// ---------------------------------------------------------------------------
__global__ __launch_bounds__(256)
void f32_to_bf16_kernel(const float* __restrict__ in, u16* __restrict__ out) {
  size_t i = ((size_t)blockIdx.x * 256 + threadIdx.x) * 8;
  float4 a = *(const float4*)(in + i);
  float4 b = *(const float4*)(in + i + 4);
  int4 v;
  v.x = (int)(f2bf(a.x) | ((uint32_t)f2bf(a.y) << 16));
  v.y = (int)(f2bf(a.z) | ((uint32_t)f2bf(a.w) << 16));
  v.z = (int)(f2bf(b.x) | ((uint32_t)f2bf(b.y) << 16));
  v.w = (int)(f2bf(b.z) | ((uint32_t)f2bf(b.w) << 16));
  *(int4*)(out + i) = v;
}

// ---------------------------------------------------------------------------
// flags[row*16 + t128] = 1 iff mask[row][t128*128 .. +128) all nonzero
__global__ __launch_bounds__(256)
void mask_flags_kernel(const int* __restrict__ mask, unsigned char* __restrict__ flags) {
  size_t row = blockIdx.x;            // b*SEQ + q
  int t = threadIdx.x;
  int t128 = t >> 4, sub = t & 15;
  const int* p = mask + row * SEQ + t128 * 128 + sub * 8;
  int4 a = *(const int4*)p;
  int4 c = *(const int4*)(p + 4);
  int ok = (a.x && a.y && a.z && a.w && c.x && c.y && c.z && c.w) ? 1 : 0;
  ok &= __shfl_xor(ok, 1);
  ok &= __shfl_xor(ok, 2);
  ok &= __shfl_xor(ok, 4);
  ok &= __shfl_xor(ok, 8);
  if (sub == 0) flags[row * 16 + t128] = (unsigned char)ok;
}

// ---------------------------------------------------------------------------
// V slice of QKV [B*S][3072] (cols 2048..3071) -> Vt bf16 [(b*NH+h)*HD + d][SEQ]
__global__ __launch_bounds__(256)
void transpose_v(const u16* __restrict__ QKV, u16* __restrict__ Vt) {
  int bh = blockIdx.x;           // 0..63
  int st = blockIdx.y;           // 0..31 (s tile of 64)
  int b = bh >> 4, h = bh & 15;
  __shared__ u16 tile[64][65];
  int t = threadIdx.x;
  int sl = t >> 2, c0 = (t & 3) * 16;
  const u16* src = QKV + (size_t)(b * SEQ + st * 64 + sl) * 3072 + 2048 + h * HD + c0;
  int4 va = *(const int4*)(src);
  int4 vb = *(const int4*)(src + 8);
  u16* tr = &tile[sl][c0];
  tr[0] = (u16)va.x; tr[1] = (u16)((uint32_t)va.x >> 16);
  tr[2] = (u16)va.y; tr[3] = (u16)((uint32_t)va.y >> 16);
  tr[4] = (u16)va.z; tr[5] = (u16)((uint32_t)va.z >> 16);
  tr[6] = (u16)va.w; tr[7] = (u16)((uint32_t)va.w >> 16);
  tr[8]  = (u16)vb.x; tr[9]  = (u16)((uint32_t)vb.x >> 16);
  tr[10] = (u16)vb.y; tr[11] = (u16)((uint32_t)vb.y >> 16);
  tr[12] = (u16)vb.z; tr[13] = (u16)((uint32_t)vb.z >> 16);
  tr[14] = (u16)vb.w; tr[15] = (u16)((uint32_t)vb.w >> 16);
  __syncthreads();
  int dl = t >> 2, s0 = (t & 3) * 16;
  uint32_t p[8];
  #pragma unroll
  for (int e = 0; e < 8; ++e)
    p[e] = (uint32_t)tile[s0 + 2*e][dl] | ((uint32_t)tile[s0 + 2*e + 1][dl] << 16);
  u16* dst = Vt + (size_t)(bh * HD + dl) * SEQ + st * 64 + s0;
  int4 o0; o0.x = (int)p[0]; o0.y = (int)p[1]; o0.z = (int)p[2]; o0.w = (int)p[3];
  int4 o1; o1.x = (int)p[4]; o1.y = (int)p[5]; o1.z = (int)p[6]; o1.w = (int)p[7];
  *(int4*)(dst) = o0;
  *(int4*)(dst + 8) = o1;
}

// ---------------------------------------------------------------------------
// GEMM (m97 structure): C[M,N] = A[M,K] bf16 @ Bt[N,K]^T bf16, fp32 acc.
// Linear LDS + global_load_lds width-16 staging. (T2 swizzle is regime-gated
// null at 128-tile 2-phase — m228d/m230 — so LDS stays linear here.)
// EPI: 0 = f32 out, 1 = bf16 out, 2 = +bias f32 out, 3 = +bias relu bf16 out
template <int EPI>
__global__ __launch_bounds__(256, 2)
void gemm_kernel(const u16* __restrict__ A, const u16* __restrict__ Bt,
                 const float* __restrict__ bias, void* __restrict__ Cout,
                 int M, int N, int K) {
  __shared__ __align__(16) u16 As[128 * 64];
  __shared__ __align__(16) u16 Bs[128 * 64];
  const int t = threadIdx.x;
  const int l = t & 63, w = t >> 6;
  const int wm = w >> 1, wn = w & 1;
  const int lg = l >> 4, lr = l & 15;
  const int row0 = blockIdx.x * 128, col0 = blockIdx.y * 128;

  f32x4 acc[4][4];
  #pragma unroll
  for (int i = 0; i < 4; ++i)
    #pragma unroll
    for (int j = 0; j < 4; ++j) acc[i][j] = (f32x4){0.f, 0.f, 0.f, 0.f};

  const int srow = w * 32 + (l >> 3);
  const int scol = (l & 7) * 8;
  const u16* Ag = A + (size_t)(row0 + srow) * K + scol;
  const u16* Bg = Bt + (size_t)(col0 + srow) * K + scol;

  const int nk = K >> 6;
  #pragma unroll
  for (int i = 0; i < 4; ++i) {
    gl16(Ag + (size_t)i * 8 * K, &As[(w * 32 + i * 8) * 64]);
    gl16(Bg + (size_t)i * 8 * K, &Bs[(w * 32 + i * 8) * 64]);
  }
  for (int kt = 0; kt < nk; ++kt) {
    __syncthreads();
    #pragma unroll
    for (int kx = 0; kx < 2; ++kx) {
      bf16x8 af[4], bf[4];
      #pragma unroll
      for (int mi = 0; mi < 4; ++mi)
        af[mi] = *(const bf16x8*)&As[(wm * 64 + mi * 16 + lr) * 64 + kx * 32 + 8 * lg];
      #pragma unroll
      for (int ni = 0; ni < 4; ++ni)
        bf[ni] = *(const bf16x8*)&Bs[(wn * 64 + ni * 16 + lr) * 64 + kx * 32 + 8 * lg];
      #pragma unroll
      for (int mi = 0; mi < 4; ++mi)
        #pragma unroll
        for (int ni = 0; ni < 4; ++ni)
          acc[mi][ni] = __builtin_amdgcn_mfma_f32_16x16x32_bf16(af[mi], bf[ni], acc[mi][ni], 0, 0, 0);
    }
    __syncthreads();
    if (kt + 1 < nk) {
      #pragma unroll
      for (int i = 0; i < 4; ++i) {
        gl16(Ag + (size_t)((kt + 1) * 64) + (size_t)i * 8 * K, &As[(w * 32 + i * 8) * 64]);
        gl16(Bg + (size_t)((kt + 1) * 64) + (size_t)i * 8 * K, &Bs[(w * 32 + i * 8) * 64]);
      }
    }
  }

  #pragma unroll
  for (int mi = 0; mi < 4; ++mi) {
    #pragma unroll
    for (int ni = 0; ni < 4; ++ni) {
      int col = col0 + wn * 64 + ni * 16 + lr;
      float badd = (EPI >= 2) ? bias[col] : 0.0f;
      #pragma unroll
      for (int r = 0; r < 4; ++r) {
        int row = row0 + wm * 64 + mi * 16 + 4 * lg + r;
        float v = acc[mi][ni][r] + badd;
        if (EPI == 3) v = fmaxf(v, 0.0f);
        if (EPI == 0 || EPI == 2)
          ((float*)Cout)[(size_t)row * N + col] = v;
        else
          ((u16*)Cout)[(size_t)row * N + col] = f2bf(v);
      }
    }
  }
}

// ---------------------------------------------------------------------------
// Flash attention: grid (S/64 q-tiles, B*NH). 4 waves, 16 q-rows each.
// KV tiles of 128, double-buffered K/V via global_load_lds with
// SOURCE-side XOR swizzle (rule #21: linear LDS dest + inverse-swizzled
// global src + swizzled ds_read) -> conflict-free b128 fragment reads.
__global__ __launch_bounds__(256, 2)
void attn_kernel(const u16* __restrict__ QKV, const u16* __restrict__ Vt,
                 const int* __restrict__ mask, const unsigned char* __restrict__ flags,
                 u16* __restrict__ Z) {
  const int qt = blockIdx.x;       // 0..31
  const int bh = blockIdx.y;       // 0..63
  const int b = bh >> 4, h = bh & 15;
  const int t = threadIdx.x;
  const int l = t & 63, w = t >> 6;
  const int lg = l >> 4, lr = l & 15;

  __shared__ __align__(16) u16 Ks[2][KVB * 64];   // [kv][d], swizzled content
  __shared__ __align__(16) u16 Vs[2][64 * KVB];   // [d][kv], swizzled content
  __shared__ __align__(16) u16 Ps[4][16 * KVB];   // per-wave P, swizzled

  const int qrow = qt * 64 + w * 16 + lr;
  const u16* qb = QKV + (size_t)(b * SEQ + qrow) * 3072 + h * HD;
  bf16x8 qf[2];
  qf[0] = *(const bf16x8*)(qb + 8 * lg);
  qf[1] = *(const bf16x8*)(qb + 32 + 8 * lg);

  float m[4], lsum[4];
  f32x4 o[4];
  #pragma unroll
  for (int r = 0; r < 4; ++r) { m[r] = -__builtin_inff(); lsum[r] = 0.f; }
  #pragma unroll
  for (int n = 0; n < 4; ++n) o[n] = (f32x4){0.f, 0.f, 0.f, 0.f};

  // --- staging addresses (source-swizzled) ---
  // K tile rows are 64 u16 = 8 slots of 16B. Lane l writes LDS slot (l&7) of
  // row (l>>3); source must supply slot ((l&7) ^ (l>>3)) so that a read of
  // slot s at row r finds global slot s^ (r&7).
  const int k_r = w * 32 + (l >> 3);
  const int k_c = ((l & 7) ^ (l >> 3)) * 8;
  const u16* Kg = QKV + (size_t)(b * SEQ) * 3072 + 1024 + h * HD;   // + row*3072
  // V tile rows are 128 u16 = 16 slots. One gl16 covers 4 rows (l>>4),
  // lane slot (l&15); source slot = (l&15) ^ (row&7).
  const u16* Vg = Vt + (size_t)(bh * HD) * SEQ;                      // + d*SEQ
  u16* ps = &Ps[w][0];

  #define STAGE(kt_, buf_)                                                     \
    {                                                                          \
      _Pragma("unroll")                                                        \
      for (int i = 0; i < 4; ++i)                                              \
        gl16(Kg + (size_t)((kt_) * KVB + k_r + i * 8) * 3072 + k_c,            \
             &Ks[buf_][(w * 32 + i * 8) * 64]);                                \
      _Pragma("unroll")                                                        \
      for (int i = 0; i < 4; ++i) {                                            \
        int vrow = w * 16 + i * 4 + (l >> 4);                                  \
        int vcol = ((l & 15) ^ (vrow & 7)) * 8;                                \
        gl16(Vg + (size_t)vrow * SEQ + (kt_) * KVB + vcol,                     \
             &Vs[buf_][(w * 16 + i * 4) * KVB]);                               \
      }                                                                        \
    }

  STAGE(0, 0);
  const int NT = SEQ / KVB;   // 16
  for (int kt = 0; kt < NT; ++kt) {
    const int cb = kt & 1;
    STAGE((kt + 1) & (NT - 1), cb ^ 1);   // prefetch next (wraps harmlessly)
    __builtin_amdgcn_sched_barrier(0);
    asm volatile("s_waitcnt vmcnt(8)" ::: "memory");   // current tile landed
    __builtin_amdgcn_sched_barrier(0);
    __builtin_amdgcn_s_barrier();

    const u16* ks = &Ks[cb][0];
    const u16* vs = &Vs[cb][0];

    // S = Q K^T  (K fragment read with matching swizzle)
    f32x4 sc[8];
    #pragma unroll
    for (int n = 0; n < 8; ++n) sc[n] = (f32x4){0.f, 0.f, 0.f, 0.f};
    #pragma unroll
    for (int kx = 0; kx < 2; ++kx)
      #pragma unroll
      for (int n = 0; n < 8; ++n) {
        bf16x8 kf = *(const bf16x8*)&ks[(n * 16 + lr) * 64 + (((kx * 4 + lg) ^ (lr & 7)) << 3)];
        sc[n] = __builtin_amdgcn_mfma_f32_16x16x32_bf16(qf[kx], kf, sc[n], 0, 0, 0);
      }

    // mask fast path
    const unsigned char* fb = flags + ((size_t)(b * SEQ) + qt * 64 + w * 16 + 4 * lg) * 16 + kt;
    int allin = fb[0] & fb[16] & fb[32] & fb[48];
    float rowm[4];
    #pragma unroll
    for (int r = 0; r < 4; ++r) rowm[r] = -__builtin_inff();
    if (__all(allin != 0)) {
      #pragma unroll
      for (int n = 0; n < 8; ++n)
        #pragma unroll
        for (int r = 0; r < 4; ++r) {
          float v = sc[n][r] * 0.25f;   // / sqrt(n_heads)
          sc[n][r] = v;
          rowm[r] = fmaxf(rowm[r], v);
        }
    } else {
      const int* mrow = mask + ((size_t)(b * SEQ) + qt * 64 + w * 16 + 4 * lg) * SEQ
                        + (size_t)kt * KVB + lr;
      #pragma unroll
      for (int n = 0; n < 8; ++n)
        #pragma unroll
        for (int r = 0; r < 4; ++r) {
          int mv = mrow[(size_t)r * SEQ + n * 16];
          float v = sc[n][r] * 0.25f;
          v = mv ? v : -1e9f;
          sc[n][r] = v;
          rowm[r] = fmaxf(rowm[r], v);
        }
    }

    // online softmax
    float alpha[4], psum[4];
    #pragma unroll
    for (int r = 0; r < 4; ++r) {
      float rm = rowm[r];
      rm = fmaxf(rm, __shfl_xor(rm, 1));
      rm = fmaxf(rm, __shfl_xor(rm, 2));
      rm = fmaxf(rm, __shfl_xor(rm, 4));
      rm = fmaxf(rm, __shfl_xor(rm, 8));
      float mn = fmaxf(m[r], rm);
      alpha[r] = __expf(m[r] - mn);
      m[r] = mn;
      psum[r] = 0.f;
    }
    #pragma unroll
    for (int n = 0; n < 8; ++n)
      #pragma unroll
      for (int r = 0; r < 4; ++r) {
        float p = __expf(sc[n][r] - m[r]);
        sc[n][r] = p;
        psum[r] += p;
      }
    #pragma unroll
    for (int r = 0; r < 4; ++r) {
      float ps_ = psum[r];
      ps_ += __shfl_xor(ps_, 1);
      ps_ += __shfl_xor(ps_, 2);
      ps_ += __shfl_xor(ps_, 4);
      ps_ += __shfl_xor(ps_, 8);
      lsum[r] = lsum[r] * alpha[r] + ps_;
      #pragma unroll
      for (int n = 0; n < 4; ++n) o[n][r] *= alpha[r];
    }

    // P -> per-wave LDS (reshape C-layout -> A-fragment layout)
    #pragma unroll
    for (int n = 0; n < 8; ++n)
      #pragma unroll
      for (int r = 0; r < 4; ++r)
        ps[swzP(4 * lg + r, n * 16 + lr)] = f2bf(sc[n][r]);
    asm volatile("s_waitcnt lgkmcnt(0)" ::: "memory");
    __builtin_amdgcn_sched_barrier(0);

    // O += P V   (V fragment read with matching swizzle)
    #pragma unroll
    for (int kx = 0; kx < 4; ++kx) {
      bf16x8 pf = *(const bf16x8*)&ps[swzP(lr, kx * 32 + 8 * lg)];
      #pragma unroll
      for (int n = 0; n < 4; ++n) {
        bf16x8 vf = *(const bf16x8*)&vs[(n * 16 + lr) * KVB + (((kx * 4 + lg) ^ (lr & 7)) << 3)];
        o[n] = __builtin_amdgcn_mfma_f32_16x16x32_bf16(pf, vf, o[n], 0, 0, 0);
      }
    }
    __builtin_amdgcn_sched_barrier(0);
    __builtin_amdgcn_s_barrier();   // all waves done reading Ks/Vs[cb]
  }
  #undef STAGE

  #pragma unroll
  for (int n = 0; n < 4; ++n)
    #pragma unroll
    for (int r = 0; r < 4; ++r) {
      int qg = qt * 64 + w * 16 + 4 * lg + r;
      float val = o[n][r] / lsum[r];
      Z[((size_t)(b * SEQ) + qg) * DM + h * HD + n * 16 + lr] = f2bf(val);
    }
}

// ---------------------------------------------------------------------------
// out = LN(a + res); optionally also bf16 copy
__global__ __launch_bounds__(256)
void ln_kernel(const float* __restrict__ a, const float* __restrict__ res,
               const float* __restrict__ g, const float* __restrict__ be,
               float* __restrict__ of, u16* __restrict__ ob) {
  int row = blockIdx.x;
  int t = threadIdx.x, l = t & 63, w = t >> 6;
  float4 va = *(const float4*)(a + (size_t)row * DM + t * 4);
  float4 vr = *(const float4*)(res + (size_t)row * DM + t * 4);
  float v0 = va.x + vr.x, v1 = va.y + vr.y, v2 = va.z + vr.z, v3 = va.w + vr.w;
  float s = v0 + v1 + v2 + v3;
  #pragma unroll
  for (int off = 32; off >= 1; off >>= 1) s += __shfl_xor(s, off);
  __shared__ float red[8];
  if (l == 0) red[w] = s;
  __syncthreads();
  float mean = (red[0] + red[1] + red[2] + red[3]) * (1.0f / DM);
  float d0 = v0 - mean, d1 = v1 - mean, d2 = v2 - mean, d3 = v3 - mean;
  float q = d0 * d0 + d1 * d1 + d2 * d2 + d3 * d3;
  #pragma unroll
  for (int off = 32; off >= 1; off >>= 1) q += __shfl_xor(q, off);
  if (l == 0) red[4 + w] = q;
  __syncthreads();
  float var = (red[4] + red[5] + red[6] + red[7]) * (1.0f / DM);
  float rstd = rsqrtf(var + 1e-5f);
  float4 gv = *(const float4*)(g + t * 4);
  float4 bv = *(const float4*)(be + t * 4);
  float o0 = d0 * rstd * gv.x + bv.x;
  float o1 = d1 * rstd * gv.y + bv.y;
  float o2 = d2 * rstd * gv.z + bv.z;
  float o3 = d3 * rstd * gv.w + bv.w;
  float4 ov; ov.x = o0; ov.y = o1; ov.z = o2; ov.w = o3;
  *(float4*)(of + (size_t)row * DM + t * 4) = ov;
  if (ob) {
    uint2 pv;
    pv.x = f2bf(o0) | ((uint32_t)f2bf(o1) << 16);
    pv.y = f2bf(o2) | ((uint32_t)f2bf(o3) << 16);
    *(uint2*)(ob + (size_t)row * DM + t * 4) = pv;
  }
}

// ---------------------------------------------------------------------------
extern "C" void kernel_launch(void* const* d_in, const int* in_sizes, int n_in,
                              void* d_out, int out_size, void* d_ws, size_t ws_size,
                              hipStream_t stream) {
  (void)in_sizes; (void)n_in; (void)out_size; (void)ws_size;
  const float* x    = (const float*)d_in[0];
  const int*   mask = (const int*)d_in[1];
  const float* Wq   = (const float*)d_in[2];
  const float* Wk   = (const float*)d_in[3];
  const float* Wv   = (const float*)d_in[4];
  const float* Wo   = (const float*)d_in[5];
  const float* ln1g = (const float*)d_in[6];
  const float* ln1b = (const float*)d_in[7];
  const float* W1   = (const float*)d_in[8];
  const float* b1   = (const float*)d_in[9];
  const float* W2   = (const float*)d_in[10];
  const float* b2   = (const float*)d_in[11];
  const float* ln2g = (const float*)d_in[12];
  const float* ln2b = (const float*)d_in[13];
  float* out = (float*)d_out;

  char* ws = (char*)d_ws;
  const size_t MB = 1024 * 1024;
  u16* WqkvT = (u16*)(ws + 0 * MB);     // 6MB: Wq^T | Wk^T | Wv^T rows
  u16* WoT   = (u16*)(ws + 6 * MB);     // 2MB
  u16* W1T   = (u16*)(ws + 8 * MB);     // 8MB [4096][1024]
  u16* W2T   = (u16*)(ws + 16 * MB);    // 8MB [1024][4096]
  u16* Xb    = (u16*)(ws + 24 * MB);    // 16MB ; Z aliases after QKV gemm
  u16* QKV   = (u16*)(ws + 40 * MB);    // 48MB [8192][3072]
  u16* Vt    = (u16*)(ws + 88 * MB);    // 16MB
  unsigned char* flags = (unsigned char*)(ws + 104 * MB);  // 128KB
  float* attn_out = (float*)(ws + 105 * MB);  // 32MB ; ff2 aliases
  u16* ff1   = (u16*)(ws + 137 * MB);   // 64MB -> total 201MB
  float* h_f32 = (float*)(ws + 40 * MB);   // over QKV (dead after attn)
  u16*   h_b16 = (u16*)(ws + 72 * MB);     // over QKV tail
  u16*   Z     = Xb;                        // attn output
  float* ff2   = attn_out;

  dim3 tb(256);
  transpose_w<<<dim3(32, 32), tb, 0, stream>>>(Wq, WqkvT, DM, DM);
  transpose_w<<<dim3(32, 32), tb, 0, stream>>>(Wk, WqkvT + (size_t)1024 * 1024, DM, DM);
  transpose_w<<<dim3(32, 32), tb, 0, stream>>>(Wv, WqkvT + (size_t)2048 * 1024, DM, DM);
  transpose_w<<<dim3(32, 32), tb, 0, stream>>>(Wo, WoT, DM, DM);
  transpose_w<<<dim3(128, 32), tb, 0, stream>>>(W1, W1T, DM, HIDN);
  transpose_w<<<dim3(32, 128), tb, 0, stream>>>(W2, W2T, HIDN, DM);

  f32_to_bf16_kernel<<<(NROWS * DM) / (256 * 8), tb, 0, stream>>>(x, Xb);
  mask_flags_kernel<<<NROWS, tb, 0, stream>>>(mask, flags);

  // fused QKV projection: [8192,1024] @ [1024,3072]
  gemm_kernel<1><<<dim3(64, 24), tb, 0, stream>>>(Xb, WqkvT, nullptr, QKV, NROWS, 3072, DM);
  transpose_v<<<dim3(64, 32), tb, 0, stream>>>(QKV, Vt);

  attn_kernel<<<dim3(32, 64), tb, 0, stream>>>(QKV, Vt, mask, flags, Z);

  gemm_kernel<0><<<dim3(64, 8), tb, 0, stream>>>(Z, WoT, nullptr, attn_out, NROWS, DM, DM);
  ln_kernel<<<NROWS, tb, 0, stream>>>(attn_out, x, ln1g, ln1b, h_f32, h_b16);
  gemm_kernel<3><<<dim3(64, 32), tb, 0, stream>>>(h_b16, W1T, b1, ff1, NROWS, HIDN, DM);
  gemm_kernel<2><<<dim3(64, 8), tb, 0, stream>>>(ff1, W2T, b2, ff2, NROWS, DM, HIDN);
  ln_kernel<<<NROWS, tb, 0, stream>>>(ff2, h_f32, ln2g, ln2b, out, nullptr);
}